// Round 14
// baseline (1576.532 us; speedup 1.0000x reference)
//
#include <hip/hip_runtime.h>

#define CDIM 128
#define KOFF 4
#define EPS 1e-4f
#define SCAN_CHUNK 2048   // 256 threads * 8 elems
#define ROWS 16           // output rows per tile (n % 16 == 0)
#define NBUF 3            // LDS ring buffers -> prefetch depth 2
#define NBLK 512          // persistent conv blocks
#define NTHR 512          // 8 waves per block
#define CAPM (1 << 18)    // multi-bucket capacity (input has ~180k)

typedef __attribute__((ext_vector_type(8))) short bf16x8;
typedef __attribute__((ext_vector_type(4))) float f32x4;

__device__ __forceinline__ unsigned short f2bf(float f) {
    unsigned int u = __builtin_bit_cast(unsigned int, f);
    u += 0x7fffu + ((u >> 16) & 1u);          // round-to-nearest-even
    return (unsigned short)(u >> 16);
}
__device__ __forceinline__ float bf2f(unsigned short h) {
    unsigned int u = ((unsigned int)h) << 16;
    return __builtin_bit_cast(float, u);
}

// async global->LDS, 16B/lane; LDS dest = wave-uniform base + lane*16
__device__ __forceinline__ void gload_lds16(const void* g, void* l) {
    __builtin_amdgcn_global_load_lds(
        (const __attribute__((address_space(1))) void*)g,
        (__attribute__((address_space(3))) void*)l, 16, 0, 0);
}

// ---------------------------------------------------------------------------
// prep: fused {count (y<4)} + {feat f32->bf16 cvt (y==4)} + {W cvt (y==5)}
// ---------------------------------------------------------------------------
__global__ __launch_bounds__(256) void prep_kernel(
    const int* __restrict__ out_idx, const int* __restrict__ mask,
    int* __restrict__ cnt, const float* __restrict__ feat,
    short* __restrict__ fb,
    const float* __restrict__ W1, const float* __restrict__ W2,
    short* __restrict__ W1t, short* __restrict__ W2t,
    int n, size_t total8)
{
    if (blockIdx.y == KOFF) {                      // cvt slice, grid-stride
        size_t stride = (size_t)gridDim.x * 256;
        for (size_t i = (size_t)blockIdx.x * 256 + threadIdx.x; i < total8; i += stride) {
            float4 a = ((const float4*)feat)[i * 2];
            float4 b = ((const float4*)feat)[i * 2 + 1];
            bf16x8 v;
            v[0] = (short)f2bf(a.x); v[1] = (short)f2bf(a.y);
            v[2] = (short)f2bf(a.z); v[3] = (short)f2bf(a.w);
            v[4] = (short)f2bf(b.x); v[5] = (short)f2bf(b.y);
            v[6] = (short)f2bf(b.z); v[7] = (short)f2bf(b.w);
            ((bf16x8*)fb)[i] = v;
        }
    } else if (blockIdx.y == KOFF + 1) {           // weight convert+transpose
        int idx = blockIdx.x * 256 + threadIdx.x;  // [k][co][ci]
        if (idx >= KOFF * CDIM * CDIM) return;
        int ci = idx & (CDIM - 1);
        int co = (idx >> 7) & (CDIM - 1);
        int k  = idx >> 14;
        size_t src = (size_t)k * CDIM * CDIM + (size_t)ci * CDIM + co;
        W1t[idx] = (short)f2bf(W1[src]);
        W2t[idx] = (short)f2bf(W2[src]);
    } else {
        int i = blockIdx.x * 256 + threadIdx.x;
        if (i >= n) return;
        int k = blockIdx.y;
        size_t s = (size_t)k * n + i;
        if (mask[s]) atomicAdd(&cnt[(size_t)out_idx[s] * KOFF + k], 1);
    }
}

// ---------------------------------------------------------------------------
// Rulebook keyed by bucket b = j*4 + k: dual scan + fused classification.
// ---------------------------------------------------------------------------
__global__ __launch_bounds__(256) void scan_p1(
    const int* __restrict__ in, int* __restrict__ bsum, int* __restrict__ bsum2, int L)
{
    __shared__ int red[256], red2[256];
    int base = blockIdx.x * SCAN_CHUNK;
    int s = 0, m = 0;
    #pragma unroll
    for (int u = 0; u < 8; ++u) {
        int i = base + u * 256 + threadIdx.x;
        if (i < L) { int v = in[i]; s += v; m += (v >= 2); }
    }
    red[threadIdx.x] = s; red2[threadIdx.x] = m;
    __syncthreads();
    for (int d = 128; d > 0; d >>= 1) {
        if (threadIdx.x < d) {
            red[threadIdx.x]  += red[threadIdx.x + d];
            red2[threadIdx.x] += red2[threadIdx.x + d];
        }
        __syncthreads();
    }
    if (threadIdx.x == 0) { bsum[blockIdx.x] = red[0]; bsum2[blockIdx.x] = red2[0]; }
}

__global__ __launch_bounds__(1024) void scan_p2(
    int* __restrict__ bsum, int* __restrict__ bsum2, int NB)
{
    __shared__ int s[1024], s2[1024];
    int t = threadIdx.x;
    s[t]  = (t < NB) ? bsum[t]  : 0;
    s2[t] = (t < NB) ? bsum2[t] : 0;
    __syncthreads();
    for (int d = 1; d < 1024; d <<= 1) {
        int x = s[t], y = s2[t];
        if (t >= d) { x += s[t - d]; y += s2[t - d]; }
        __syncthreads();
        s[t] = x; s2[t] = y;
        __syncthreads();
    }
    if (t < NB) {
        bsum[t]  = (t == 0) ? 0 : s[t - 1];     // exclusive
        bsum2[t] = (t == 0) ? 0 : s2[t - 1];
    }
}

__global__ __launch_bounds__(256) void scan_p3(
    const int* __restrict__ cnt, const int* __restrict__ bsum,
    const int* __restrict__ bsum2, int* __restrict__ off_start,
    int* __restrict__ fcur, int* __restrict__ prim,
    int* __restrict__ mlist, int* __restrict__ nmulti, int L, int KN)
{
    __shared__ int ts[256], ms[256];
    int t = threadIdx.x;
    int base = blockIdx.x * SCAN_CHUNK + t * 8;
    int v[8]; int s = 0, m = 0;
    #pragma unroll
    for (int u = 0; u < 8; ++u) {
        int i = base + u;
        v[u] = (i < L) ? cnt[i] : 0;
        s += v[u]; m += (v[u] >= 2);
    }
    ts[t] = s; ms[t] = m;
    __syncthreads();
    for (int d = 1; d < 256; d <<= 1) {
        int x = ts[t], y = ms[t];
        if (t >= d) { x += ts[t - d]; y += ms[t - d]; }
        __syncthreads();
        ts[t] = x; ms[t] = y;
        __syncthreads();
    }
    int pre  = bsum[blockIdx.x]  + ((t == 0) ? 0 : ts[t - 1]);
    int mpre = bsum2[blockIdx.x] + ((t == 0) ? 0 : ms[t - 1]);
    #pragma unroll
    for (int u = 0; u < 8; ++u) {
        int i = base + u;
        if (i < L) {
            off_start[i] = pre;
            fcur[i] = pre;
            if (i < KN) {
                int c = v[u];
                if (c == 0) prim[i] = -1;
                else if (c >= 2) {
                    if (mpre < CAPM) { prim[i] = 0x40000000 | mpre; mlist[mpre] = i; }
                    else prim[i] = -1;
                }
            } else {
                nmulti[0] = mpre;
            }
            pre += v[u]; mpre += (v[u] >= 2);
        }
    }
}

__global__ __launch_bounds__(256) void fill_kernel(
    const int* __restrict__ out_idx, const int* __restrict__ in_idx,
    const int* __restrict__ mask, const int* __restrict__ cnt,
    int* __restrict__ fcur, int* __restrict__ ent, int* __restrict__ prim, int n)
{
    int i = blockIdx.x * 256 + threadIdx.x;
    if (i >= n) return;
    int k = blockIdx.y;
    size_t s = (size_t)k * n + i;
    if (mask[s]) {
        int j = out_idx[s];
        size_t b = (size_t)j * KOFF + k;
        int src = in_idx[s];
        if (cnt[b] == 1) prim[b] = src;                 // single: direct, no atomic
        else { int pos = atomicAdd(&fcur[b], 1); ent[pos] = src; }
    }
}

// ---------------------------------------------------------------------------
// merge: sumbuf[i] = bf16( sum of X rows of multi-bucket mlist[i] )
// ---------------------------------------------------------------------------
__global__ __launch_bounds__(256) void merge_kernel(
    const short* __restrict__ Xb, const int* __restrict__ off_start,
    const int* __restrict__ ent, const int* __restrict__ mlist,
    const int* __restrict__ nmulti, short* __restrict__ sumbuf)
{
    int nm = *nmulti; if (nm > CAPM) nm = CAPM;
    int grp  = (blockIdx.x * 256 + threadIdx.x) >> 5;
    int gl   = threadIdx.x & 31;
    int ngrp = (gridDim.x * 256) >> 5;
    for (int i = grp; i < nm; i += ngrp) {
        int b  = mlist[i];
        int e0 = off_start[b];
        int e1 = off_start[b + 1];
        float a0 = 0.f, a1 = 0.f, a2 = 0.f, a3 = 0.f;
        for (int e = e0; e < e1; ++e) {
            int src = ent[e];
            ushort4 v = *((const ushort4*)(Xb + (size_t)src * CDIM) + gl);
            a0 += bf2f(v.x); a1 += bf2f(v.y); a2 += bf2f(v.z); a3 += bf2f(v.w);
        }
        ushort4 o;
        o.x = f2bf(a0); o.y = f2bf(a1); o.z = f2bf(a2); o.w = f2bf(a3);
        *((ushort4*)(sumbuf + (size_t)i * CDIM) + gl) = o;
    }
}

// ---------------------------------------------------------------------------
// Persistent weight-stationary conv, depth-2 DMA pipeline, 3 blocks/CU.
// ROWS=16 tiles, 3 LDS ring buffers (49 KB total): iteration ti stages tile
// ti+2 while computing tile ti.  24 waves/CU.  Exact counted vmcnt (N = vmem
// ops issued after the target STAGE group, all unconditional):
//   steady: EPI0 12, EPI1 14; ramp k=0: 8/9, k=1: 11/13.
// EPI1 residual float4 pre-issued before STAGE (off the epilogue path).
// Raw s_barrier only (syncthreads would drain vmcnt to 0).
// ---------------------------------------------------------------------------
template <int EPI>
__global__ __launch_bounds__(NTHR, 6) void conv_kernel(
    const short* __restrict__ Xb, const short* __restrict__ sumbuf,
    const short* __restrict__ Wt, const int* __restrict__ prim,
    const char* __restrict__ zpage,
    const float* __restrict__ gamma, const float* __restrict__ beta,
    const float* __restrict__ mean, const float* __restrict__ var,
    const float* __restrict__ feat, void* __restrict__ Yv,
    int n, int ntile, int tpb)
{
    const int t    = threadIdx.x;
    const int w    = t >> 6;                   // wave 0..7
    const int lane = t & 63;

    __shared__ alignas(16) short As[NBUF][ROWS * 512];   // 3 x 16 KB ring
    __shared__ alignas(16) float s_scale[CDIM], s_shift[CDIM];

    if (t < CDIM) {
        float sc = gamma[t] * rsqrtf(var[t] + EPS);
        s_scale[t] = sc;
        s_shift[t] = beta[t] - mean[t] * sc;
    }
    __syncthreads();

    int t0 = blockIdx.x * tpb;
    int t1 = min(t0 + tpb, ntile);
    if (t0 >= t1) return;

    const int q    = lane >> 4;                // k segment (staging)
    const int p    = lane & 15;                // 16B chunk in segment
    const int lrow = lane & 15;
    const int g2   = lane >> 4;
    const int col  = w * 16 + lrow;            // this thread's cout column

    // ---- W cout-16 slice -> VGPRs, once per block (16 frags = 64 VGPR) ----
    bf16x8 wfr[16];
    #pragma unroll
    for (int ks = 0; ks < 16; ++ks) {
        int k  = ks >> 2;
        int kk = ks & 3;
        wfr[ks] = *(const bf16x8*)(Wt + (size_t)k * CDIM * CDIM
                                   + (w * 16 + lrow) * CDIM + kk * 32 + g2 * 8);
    }

    // prim loads: tile index clamped (tail stages redundant data, counts stable)
    auto LOADP = [&](int ti, int* pr) {
        int tc = (ti < t1) ? ti : (t1 - 1);
        int j0 = tc * ROWS;
        #pragma unroll
        for (int i = 0; i < 2; ++i)
            pr[i] = prim[(size_t)(j0 + w * 2 + i) * KOFF + q];
    };
    auto STAGE = [&](const int* pr, int buf) {
        #pragma unroll
        for (int i = 0; i < 2; ++i) {
            int jl = w * 2 + i;
            int boff = ((p ^ (jl & 7)) << 4);
            int pv = pr[i];
            const char* g;
            if (pv < 0)               g = zpage + boff;
            else if (pv & 0x40000000) g = (const char*)sumbuf + ((size_t)(pv & 0x3FFFFFFF) << 8) + boff;
            else                      g = (const char*)Xb + ((size_t)pv << 8) + boff;
            gload_lds16(g, (char*)As[buf] + jl * 1024);
        }
    };

    // one pipeline iteration; VMW = exact counted vmcnt for this position
    auto ITER = [&](int ti, int rb, int sb, const int* prS, int* prL, auto&& VMW) {
        // pre-issue residual load (EPI1) so its latency hides under MFMA
        float4 fpre;
        int erow = t >> 5, ec4 = t & 31;       // 512 thr = 16 rows * 32 float4
        if (EPI == 1)
            fpre = ((const float4*)feat)[(size_t)(ti * ROWS + erow) * 32 + ec4];

        STAGE(prS, sb);                        // tile ti+2 -> buffer sb
        LOADP(ti + 3, prL);                    // prim for tile ti+3
        VMW();                                 // tile ti's DMAs provably done
        __builtin_amdgcn_s_barrier();          // B1: As[rb] ready
        __builtin_amdgcn_sched_barrier(0);

        f32x4 acc = (f32x4){0.f, 0.f, 0.f, 0.f};
        __builtin_amdgcn_s_setprio(1);
        #pragma unroll
        for (int ks = 0; ks < 16; ++ks) {
            int cb = ks * 4 + g2;
            bf16x8 a = *(const bf16x8*)(&As[rb][lrow * 512 + ((cb ^ (lrow & 7)) << 3)]);
            acc = __builtin_amdgcn_mfma_f32_16x16x32_bf16(a, wfr[ks], acc, 0, 0, 0);
        }
        __builtin_amdgcn_s_setprio(0);
        asm volatile("s_waitcnt lgkmcnt(0)" ::: "memory");
        __builtin_amdgcn_s_barrier();          // B2: As[rb] reads done

        float* Ot = (float*)As[rb];            // 16 x 132 f32 (8.4 KB)
        #pragma unroll
        for (int jj = 0; jj < 4; ++jj)
            Ot[(g2 * 4 + jj) * 132 + col] = acc[jj];
        asm volatile("s_waitcnt lgkmcnt(0)" ::: "memory");
        __builtin_amdgcn_s_barrier();          // B3: Ot written

        {
            int grow = ti * ROWS + erow;
            if (grow < n) {                    // always true (n % 16 == 0)
                float4 x  = *(const float4*)(Ot + erow * 132 + ec4 * 4);
                float4 sc = ((const float4*)s_scale)[ec4];
                float4 sh = ((const float4*)s_shift)[ec4];
                size_t go = (size_t)grow * 32 + ec4;
                if (EPI == 0) {
                    ushort4 o;
                    o.x = f2bf(fmaxf(x.x * sc.x + sh.x, 0.f));
                    o.y = f2bf(fmaxf(x.y * sc.y + sh.y, 0.f));
                    o.z = f2bf(fmaxf(x.z * sc.z + sh.z, 0.f));
                    o.w = f2bf(fmaxf(x.w * sc.w + sh.w, 0.f));
                    ((ushort4*)Yv)[go] = o;
                } else {
                    float4 r;
                    r.x = x.x * sc.x + sh.x + fpre.x;
                    r.y = x.y * sc.y + sh.y + fpre.y;
                    r.z = x.z * sc.z + sh.z + fpre.z;
                    r.w = x.w * sc.w + sh.w + fpre.w;
                    ((float4*)Yv)[go] = r;
                }
            }
        }
        asm volatile("s_waitcnt lgkmcnt(0)" ::: "memory");
        __builtin_amdgcn_s_barrier();          // B4: Ot reads done (buffer free)
    };

    #define VMW_LIT(N0, N1)                                                     \
        [] {                                                                    \
            if (EPI == 0) asm volatile("s_waitcnt vmcnt(" #N0 ")" ::: "memory");\
            else          asm volatile("s_waitcnt vmcnt(" #N1 ")" ::: "memory");\
        }

    int pA[2], pB[2], pC[2];
    LOADP(t0,     pA);
    LOADP(t0 + 1, pB);
    STAGE(pA, 0);
    STAGE(pB, 1);
    LOADP(t0 + 2, pC);

    // ramp (exact counts; block-uniform guards keep barriers safe)
    ITER(t0 + 0, 0, 2, pC, pA, VMW_LIT(8, 9));
    if (t0 + 1 < t1) {
        ITER(t0 + 1, 1, 0, pA, pB, VMW_LIT(11, 13));
        if (t0 + 2 < t1) {
            ITER(t0 + 2, 2, 1, pB, pC, VMW_LIT(12, 14));
            for (int ti = t0 + 3; ti < t1; ti += 3) {
                ITER(ti, 0, 2, pC, pA, VMW_LIT(12, 14));
                if (ti + 1 >= t1) break;
                ITER(ti + 1, 1, 0, pA, pB, VMW_LIT(12, 14));
                if (ti + 2 >= t1) break;
                ITER(ti + 2, 2, 1, pB, pC, VMW_LIT(12, 14));
            }
        }
    }
    #undef VMW_LIT
}

extern "C" void kernel_launch(void* const* d_in, const int* in_sizes, int n_in,
                              void* d_out, int out_size, void* d_ws, size_t ws_size,
                              hipStream_t stream)
{
    const float* feat   = (const float*)d_in[0];
    const float* W1     = (const float*)d_in[1];
    const float* W2     = (const float*)d_in[2];
    const float* gamma1 = (const float*)d_in[3];
    const float* beta1  = (const float*)d_in[4];
    const float* mean1  = (const float*)d_in[5];
    const float* var1   = (const float*)d_in[6];
    const float* gamma2 = (const float*)d_in[7];
    const float* beta2  = (const float*)d_in[8];
    const float* mean2  = (const float*)d_in[9];
    const float* var2   = (const float*)d_in[10];
    const int* in_idx   = (const int*)d_in[11];
    const int* out_idx  = (const int*)d_in[12];
    const int* mask     = (const int*)d_in[13];

    const int n  = in_sizes[0] / CDIM;     // 500000 (src < 2^19, n % 16 == 0)
    const int KN = KOFF * n;
    const int L  = KN + 1;
    const int NB = (L + SCAN_CHUNK - 1) / SCAN_CHUNK;   // 977 <= 1024
    const size_t nelem = (size_t)n * CDIM;

    auto alignup = [](size_t x) { return (x + 255) & ~(size_t)255; };
    char* p = (char*)d_ws;
    int*   cnt    = (int*)p;    p += alignup((size_t)L * 4);
    int*   offs   = (int*)p;    p += alignup((size_t)L * 4);   // off_start
    int*   fcur   = (int*)p;    p += alignup((size_t)L * 4);
    int*   bsum   = (int*)p;    p += alignup(4096 * 4);
    int*   bsum2  = (int*)p;    p += alignup(4096 * 4);
    int*   ent    = (int*)p;    p += alignup((size_t)KN * 4);
    int*   prim   = (int*)p;    p += alignup((size_t)KN * 4);
    int*   mlist  = (int*)p;    p += alignup((size_t)CAPM * 4);
    int*   nmulti = (int*)p;    p += 256;
    short* W1t    = (short*)p;  p += alignup((size_t)KOFF * CDIM * CDIM * 2);
    short* W2t    = (short*)p;  p += alignup((size_t)KOFF * CDIM * CDIM * 2);
    char*  zpage  = p;          p += 256;
    short* sumbuf = (short*)p;  p += alignup((size_t)CAPM * CDIM * 2);  // 64 MB
    short* h1b    = (short*)p;                 // n*128 bf16 = 128 MB
    short* fb     = (short*)d_out;             // bf16 feat parks in d_out

    // rulebook + conversions (cvt + wconv fused into prep)
    hipMemsetAsync(cnt, 0, (size_t)L * 4, stream);
    hipMemsetAsync(zpage, 0, 256, stream);
    dim3 pg((n + 255) / 256, KOFF + 2);
    prep_kernel<<<pg, 256, 0, stream>>>(out_idx, mask, cnt, feat, fb,
                                        W1, W2, W1t, W2t, n, nelem / 8);
    scan_p1<<<NB, 256, 0, stream>>>(cnt, bsum, bsum2, L);
    scan_p2<<<1, 1024, 0, stream>>>(bsum, bsum2, NB);
    scan_p3<<<NB, 256, 0, stream>>>(cnt, bsum, bsum2, offs, fcur, prim, mlist, nmulti, L, KN);
    dim3 fg((n + 255) / 256, KOFF);
    fill_kernel<<<fg, 256, 0, stream>>>(out_idx, in_idx, mask, cnt, fcur, ent, prim, n);

    const int ntile = n / ROWS;                        // 31250 exact
    const int tpb   = (ntile + NBLK - 1) / NBLK;       // 62

    // conv1
    merge_kernel<<<1024, 256, 0, stream>>>(fb, offs, ent, mlist, nmulti, sumbuf);
    conv_kernel<0><<<NBLK, NTHR, 0, stream>>>(
        fb, sumbuf, W1t, prim, zpage, gamma1, beta1, mean1, var1, nullptr, h1b, n, ntile, tpb);
    // conv2 (sumbuf recomputed from h1b)
    merge_kernel<<<1024, 256, 0, stream>>>(h1b, offs, ent, mlist, nmulti, sumbuf);
    conv_kernel<1><<<NBLK, NTHR, 0, stream>>>(
        h1b, sumbuf, W2t, prim, zpage, gamma2, beta2, mean2, var2, feat, d_out, n, ntile, tpb);
}

// Round 16
// 619.904 us; speedup vs baseline: 2.5432x; 2.5432x over previous
//
#include <hip/hip_runtime.h>

#define CDIM 128
#define KOFF 4
#define EPS 1e-4f
#define SCAN_CHUNK 2048   // 256 threads * 8 elems
#define ROWS 16           // output rows per tile (n % 16 == 0)
#define NBUF 4            // LDS ring buffers -> prefetch depth 3
#define NBLK 512          // persistent conv blocks (2 per CU)
#define NTHR 512          // 8 waves per block
#define CAPM (1 << 18)    // multi-bucket capacity (input has ~180k)

typedef __attribute__((ext_vector_type(8))) short bf16x8;
typedef __attribute__((ext_vector_type(4))) float f32x4;

__device__ __forceinline__ unsigned short f2bf(float f) {
    unsigned int u = __builtin_bit_cast(unsigned int, f);
    u += 0x7fffu + ((u >> 16) & 1u);          // round-to-nearest-even
    return (unsigned short)(u >> 16);
}
__device__ __forceinline__ float bf2f(unsigned short h) {
    unsigned int u = ((unsigned int)h) << 16;
    return __builtin_bit_cast(float, u);
}

// async global->LDS, 16B/lane; LDS dest = wave-uniform base + lane*16
__device__ __forceinline__ void gload_lds16(const void* g, void* l) {
    __builtin_amdgcn_global_load_lds(
        (const __attribute__((address_space(1))) void*)g,
        (__attribute__((address_space(3))) void*)l, 16, 0, 0);
}

// ---------------------------------------------------------------------------
// prep: fused {count (y<4)} + {feat cvt (y==4)} + {W cvt + zpage zero (y==5)}
// ---------------------------------------------------------------------------
__global__ __launch_bounds__(256) void prep_kernel(
    const int* __restrict__ out_idx, const int* __restrict__ mask,
    int* __restrict__ cnt, const float* __restrict__ feat,
    short* __restrict__ fb,
    const float* __restrict__ W1, const float* __restrict__ W2,
    short* __restrict__ W1t, short* __restrict__ W2t, int* __restrict__ zpage,
    int n, size_t total8)
{
    if (blockIdx.y == KOFF) {                      // cvt slice, grid-stride
        size_t stride = (size_t)gridDim.x * 256;
        for (size_t i = (size_t)blockIdx.x * 256 + threadIdx.x; i < total8; i += stride) {
            float4 a = ((const float4*)feat)[i * 2];
            float4 b = ((const float4*)feat)[i * 2 + 1];
            bf16x8 v;
            v[0] = (short)f2bf(a.x); v[1] = (short)f2bf(a.y);
            v[2] = (short)f2bf(a.z); v[3] = (short)f2bf(a.w);
            v[4] = (short)f2bf(b.x); v[5] = (short)f2bf(b.y);
            v[6] = (short)f2bf(b.z); v[7] = (short)f2bf(b.w);
            ((bf16x8*)fb)[i] = v;
        }
    } else if (blockIdx.y == KOFF + 1) {           // W convert + zpage zero
        if (blockIdx.x == 0 && threadIdx.x < 64) zpage[threadIdx.x] = 0;
        int idx = blockIdx.x * 256 + threadIdx.x;  // [k][co][ci]
        if (idx >= KOFF * CDIM * CDIM) return;
        int ci = idx & (CDIM - 1);
        int co = (idx >> 7) & (CDIM - 1);
        int k  = idx >> 14;
        size_t src = (size_t)k * CDIM * CDIM + (size_t)ci * CDIM + co;
        W1t[idx] = (short)f2bf(W1[src]);
        W2t[idx] = (short)f2bf(W2[src]);
    } else {
        int i = blockIdx.x * 256 + threadIdx.x;
        if (i >= n) return;
        int k = blockIdx.y;
        size_t s = (size_t)k * n + i;
        if (mask[s]) atomicAdd(&cnt[(size_t)out_idx[s] * KOFF + k], 1);
    }
}

// ---------------------------------------------------------------------------
// Single-kernel decoupled-lookback dual scan + fused classification.
//   agg[bid] u64: state[63:62] (0 invalid, 1 aggregate, 2 inclusive),
//                 sum[55:24], multi[23:0].  Device-scope atomics only.
// ---------------------------------------------------------------------------
__device__ __forceinline__ unsigned long long lb_pack(int st, int s, int m) {
    return ((unsigned long long)st << 62) |
           ((unsigned long long)(unsigned)s << 24) |
           (unsigned long long)(unsigned)m;
}

__global__ __launch_bounds__(256) void scan_lb_kernel(
    const int* __restrict__ cnt, int* __restrict__ fcur, int* __restrict__ prim,
    int* __restrict__ mlist, int* __restrict__ nmulti,
    unsigned long long* __restrict__ agg, int* __restrict__ wgctr, int L, int KN)
{
    __shared__ int ts[256], ms[256];
    __shared__ int s_bid, s_ps, s_pm;
    int t = threadIdx.x;
    if (t == 0) s_bid = atomicAdd(wgctr, 1);      // dynamic order = schedule order
    __syncthreads();
    const int bid = s_bid;
    int base = bid * SCAN_CHUNK + t * 8;

    int v[8]; int s = 0, m = 0;
    #pragma unroll
    for (int u = 0; u < 8; ++u) {
        int i = base + u;
        v[u] = (i < L) ? cnt[i] : 0;
        s += v[u]; m += (v[u] >= 2);
    }
    ts[t] = s; ms[t] = m;
    __syncthreads();
    for (int d = 1; d < 256; d <<= 1) {
        int x = ts[t], y = ms[t];
        if (t >= d) { x += ts[t - d]; y += ms[t - d]; }
        __syncthreads();
        ts[t] = x; ms[t] = y;
        __syncthreads();
    }

    if (t == 0) {
        int bs = ts[255], bm = ms[255];
        if (bid == 0) {
            atomicExch(&agg[0], lb_pack(2, bs, bm));
            s_ps = 0; s_pm = 0;
        } else {
            atomicExch(&agg[bid], lb_pack(1, bs, bm));
            int exs = 0, exm = 0, pred = bid - 1;
            while (true) {
                unsigned long long x;
                do { x = atomicAdd(&agg[pred], 0ULL); } while ((x >> 62) == 0ULL);
                exm += (int)(x & 0xFFFFFFULL);
                exs += (int)((x >> 24) & 0xFFFFFFFFULL);
                if ((x >> 62) == 2ULL) break;
                --pred;
            }
            atomicExch(&agg[bid], lb_pack(2, exs + bs, exm + bm));
            s_ps = exs; s_pm = exm;
        }
    }
    __syncthreads();

    int pre  = s_ps + ((t == 0) ? 0 : ts[t - 1]);
    int mpre = s_pm + ((t == 0) ? 0 : ms[t - 1]);
    #pragma unroll
    for (int u = 0; u < 8; ++u) {
        int i = base + u;
        if (i < L) {
            fcur[i] = pre;
            if (i < KN) {
                int c = v[u];
                if (c == 0) prim[i] = -1;
                else if (c >= 2) {
                    if (mpre < CAPM) { prim[i] = 0x40000000 | mpre; mlist[mpre] = i; }
                    else prim[i] = -1;
                }
            } else {
                nmulti[0] = mpre;
            }
            pre += v[u]; mpre += (v[u] >= 2);
        }
    }
}

__global__ __launch_bounds__(256) void fill_kernel(
    const int* __restrict__ out_idx, const int* __restrict__ in_idx,
    const int* __restrict__ mask, const int* __restrict__ cnt,
    int* __restrict__ fcur, int* __restrict__ ent, int* __restrict__ prim, int n)
{
    int i = blockIdx.x * 256 + threadIdx.x;
    if (i >= n) return;
    int k = blockIdx.y;
    size_t s = (size_t)k * n + i;
    if (mask[s]) {
        int j = out_idx[s];
        size_t b = (size_t)j * KOFF + k;
        int src = in_idx[s];
        if (cnt[b] == 1) prim[b] = src;                 // single: direct, no atomic
        else { int pos = atomicAdd(&fcur[b], 1); ent[pos] = src; }
    }
}
// post-fill: for multi buckets fcur[b] = END; start = fcur[b] - cnt[b]

// ---------------------------------------------------------------------------
// merge: sumbuf[i] = bf16( sum of X rows of multi-bucket mlist[i] )
// ---------------------------------------------------------------------------
__global__ __launch_bounds__(256) void merge_kernel(
    const short* __restrict__ Xb, const int* __restrict__ fcur,
    const int* __restrict__ cnt, const int* __restrict__ ent,
    const int* __restrict__ mlist, const int* __restrict__ nmulti,
    short* __restrict__ sumbuf)
{
    int nm = *nmulti; if (nm > CAPM) nm = CAPM;
    int grp  = (blockIdx.x * 256 + threadIdx.x) >> 5;
    int gl   = threadIdx.x & 31;
    int ngrp = (gridDim.x * 256) >> 5;
    for (int i = grp; i < nm; i += ngrp) {
        int b  = mlist[i];
        int e1 = fcur[b];
        int e0 = e1 - cnt[b];
        float a0 = 0.f, a1 = 0.f, a2 = 0.f, a3 = 0.f;
        for (int e = e0; e < e1; ++e) {
            int src = ent[e];
            ushort4 v = *((const ushort4*)(Xb + (size_t)src * CDIM) + gl);
            a0 += bf2f(v.x); a1 += bf2f(v.y); a2 += bf2f(v.z); a3 += bf2f(v.w);
        }
        ushort4 o;
        o.x = f2bf(a0); o.y = f2bf(a1); o.z = f2bf(a2); o.w = f2bf(a3);
        *((ushort4*)(sumbuf + (size_t)i * CDIM) + gl) = o;
    }
}

// ---------------------------------------------------------------------------
// Persistent weight-stationary conv, depth-3 DMA pipeline, 2 barriers/tile.
// R13 ring structure (ROWS=16, NBUF=4) + direct C-fragment epilogue:
// BN applied in registers, stores are 32B(bf16)/64B(f32) contiguous per
// 16-lane row group on dense rows (L2 merges lines -> no HBM inflation).
// Exact counted vmcnt (window = ops issued after target STAGE; sched_barrier
// pins window boundaries): ramp 10/14, 16/24, 22/34; steady EPI0 26, EPI1 38.
// launch_bounds(512,4): VGPR budget 128 so wfr[16] (64 regs) stays resident
// (R14 lesson: (512,6) -> 80-reg cap -> W rematerialized, 8x FETCH).
// ---------------------------------------------------------------------------
template <int EPI>
__global__ __launch_bounds__(NTHR, 4) void conv_kernel(
    const short* __restrict__ Xb, const short* __restrict__ sumbuf,
    const short* __restrict__ Wt, const int* __restrict__ prim,
    const char* __restrict__ zpage,
    const float* __restrict__ gamma, const float* __restrict__ beta,
    const float* __restrict__ mean, const float* __restrict__ var,
    const float* __restrict__ feat, void* __restrict__ Yv,
    int n, int ntile, int tpb)
{
    const int t    = threadIdx.x;
    const int w    = t >> 6;                   // wave 0..7
    const int lane = t & 63;

    __shared__ alignas(16) short As[NBUF][ROWS * 512];   // 4 x 16 KB ring
    __shared__ alignas(16) float s_scale[CDIM], s_shift[CDIM];

    if (t < CDIM) {
        float sc = gamma[t] * rsqrtf(var[t] + EPS);
        s_scale[t] = sc;
        s_shift[t] = beta[t] - mean[t] * sc;
    }
    __syncthreads();

    int t0 = blockIdx.x * tpb;
    int t1 = min(t0 + tpb, ntile);
    if (t0 >= t1) return;

    const int q    = lane >> 4;                // k segment (staging)
    const int p    = lane & 15;                // 16B chunk in segment
    const int lrow = lane & 15;
    const int g2   = lane >> 4;
    const int col  = w * 16 + lrow;            // this thread's cout column

    const float csc = s_scale[col];
    const float csh = s_shift[col];

    // ---- W cout-16 slice -> VGPRs, once per block (16 frags = 64 VGPR) ----
    bf16x8 wfr[16];
    #pragma unroll
    for (int ks = 0; ks < 16; ++ks) {
        int k  = ks >> 2;
        int kk = ks & 3;
        wfr[ks] = *(const bf16x8*)(Wt + (size_t)k * CDIM * CDIM
                                   + (w * 16 + lrow) * CDIM + kk * 32 + g2 * 8);
    }

    auto LOADP = [&](int ti, int* pr) {
        int tc = (ti < t1) ? ti : (t1 - 1);    // clamp: tail loads stay issued
        int j0 = tc * ROWS;
        #pragma unroll
        for (int i = 0; i < 2; ++i)
            pr[i] = prim[(size_t)(j0 + w * 2 + i) * KOFF + q];
    };
    auto STAGE = [&](const int* pr, int buf) {
        #pragma unroll
        for (int i = 0; i < 2; ++i) {
            int jl = w * 2 + i;
            int boff = ((p ^ (jl & 7)) << 4);
            int pv = pr[i];
            const char* g;
            if (pv < 0)               g = zpage + boff;
            else if (pv & 0x40000000) g = (const char*)sumbuf + ((size_t)(pv & 0x3FFFFFFF) << 8) + boff;
            else                      g = (const char*)Xb + ((size_t)pv << 8) + boff;
            gload_lds16(g, (char*)As[buf] + jl * 1024);
        }
    };

    // one pipeline iteration; VMW = exact counted vmcnt for this position
    auto ITER = [&](int ti, int rb, int sb, const int* prS, int* prL, auto&& VMW) {
        // residual preloads (EPI1) in C-fragment layout, issued first
        float fres[4];
        if (EPI == 1) {
            #pragma unroll
            for (int jj = 0; jj < 4; ++jj)
                fres[jj] = feat[(size_t)(ti * ROWS + g2 * 4 + jj) * CDIM + col];
        }
        STAGE(prS, sb);                        // tile ti+3 -> buffer sb
        LOADP(ti + 4, prL);                    // prim for tile ti+4
        __builtin_amdgcn_sched_barrier(0);     // pin window before the wait
        VMW();                                 // tile ti's DMAs provably done
        __builtin_amdgcn_s_barrier();          // B1: As[rb] ready
        __builtin_amdgcn_sched_barrier(0);

        f32x4 acc = (f32x4){0.f, 0.f, 0.f, 0.f};
        __builtin_amdgcn_s_setprio(1);
        #pragma unroll
        for (int ks = 0; ks < 16; ++ks) {
            int cb = ks * 4 + g2;
            bf16x8 a = *(const bf16x8*)(&As[rb][lrow * 512 + ((cb ^ (lrow & 7)) << 3)]);
            acc = __builtin_amdgcn_mfma_f32_16x16x32_bf16(a, wfr[ks], acc, 0, 0, 0);
        }
        __builtin_amdgcn_s_setprio(0);
        asm volatile("s_waitcnt lgkmcnt(0)" ::: "memory");
        __builtin_amdgcn_s_barrier();          // B2: As[rb] reads done -> reusable

        // direct epilogue: BN in regs, per-16-lane-group contiguous row chunks
        if (EPI == 0) {
            unsigned short* out = (unsigned short*)Yv;
            #pragma unroll
            for (int jj = 0; jj < 4; ++jj) {
                int row = ti * ROWS + g2 * 4 + jj;
                out[(size_t)row * CDIM + col] = f2bf(fmaxf(acc[jj] * csc + csh, 0.f));
            }
        } else {
            float* out = (float*)Yv;
            #pragma unroll
            for (int jj = 0; jj < 4; ++jj) {
                int row = ti * ROWS + g2 * 4 + jj;
                out[(size_t)row * CDIM + col] = acc[jj] * csc + csh + fres[jj];
            }
        }
        __builtin_amdgcn_sched_barrier(0);     // pin stores inside this window
    };

    #define VMW_LIT(N0, N1)                                                     \
        [] {                                                                    \
            if (EPI == 0) asm volatile("s_waitcnt vmcnt(" #N0 ")" ::: "memory");\
            else          asm volatile("s_waitcnt vmcnt(" #N1 ")" ::: "memory");\
        }

    int p0[2], p1[2], p2[2], p3[2];
    LOADP(t0,     p0);
    LOADP(t0 + 1, p1);
    LOADP(t0 + 2, p2);
    STAGE(p0, 0);
    STAGE(p1, 1);
    STAGE(p2, 2);
    LOADP(t0 + 3, p3);

    // ramp (exact counts; block-uniform guards keep barriers safe)
    ITER(t0 + 0, 0, 3, p3, p0, VMW_LIT(10, 14));
    if (t0 + 1 < t1) {
        ITER(t0 + 1, 1, 0, p0, p1, VMW_LIT(16, 24));
        if (t0 + 2 < t1) {
            ITER(t0 + 2, 2, 1, p1, p2, VMW_LIT(22, 34));
            if (t0 + 3 < t1) {
                ITER(t0 + 3, 3, 2, p2, p3, VMW_LIT(26, 38));
                for (int ti = t0 + 4; ti < t1; ti += 4) {
                    ITER(ti, 0, 3, p3, p0, VMW_LIT(26, 38));
                    if (ti + 1 >= t1) break;
                    ITER(ti + 1, 1, 0, p0, p1, VMW_LIT(26, 38));
                    if (ti + 2 >= t1) break;
                    ITER(ti + 2, 2, 1, p1, p2, VMW_LIT(26, 38));
                    if (ti + 3 >= t1) break;
                    ITER(ti + 3, 3, 2, p2, p3, VMW_LIT(26, 38));
                }
            }
        }
    }
    #undef VMW_LIT
}

extern "C" void kernel_launch(void* const* d_in, const int* in_sizes, int n_in,
                              void* d_out, int out_size, void* d_ws, size_t ws_size,
                              hipStream_t stream)
{
    const float* feat   = (const float*)d_in[0];
    const float* W1     = (const float*)d_in[1];
    const float* W2     = (const float*)d_in[2];
    const float* gamma1 = (const float*)d_in[3];
    const float* beta1  = (const float*)d_in[4];
    const float* mean1  = (const float*)d_in[5];
    const float* var1   = (const float*)d_in[6];
    const float* gamma2 = (const float*)d_in[7];
    const float* beta2  = (const float*)d_in[8];
    const float* mean2  = (const float*)d_in[9];
    const float* var2   = (const float*)d_in[10];
    const int* in_idx   = (const int*)d_in[11];
    const int* out_idx  = (const int*)d_in[12];
    const int* mask     = (const int*)d_in[13];

    const int n  = in_sizes[0] / CDIM;     // 500000 (src < 2^19, n % 16 == 0)
    const int KN = KOFF * n;
    const int L  = KN + 1;
    const int NB = (L + SCAN_CHUNK - 1) / SCAN_CHUNK;   // 977
    const size_t nelem = (size_t)n * CDIM;

    auto alignup = [](size_t x) { return (x + 255) & ~(size_t)255; };
    char* p = (char*)d_ws;
    int*   cnt    = (int*)p;    p += alignup((size_t)L * 4);
    unsigned long long* agg = (unsigned long long*)p; p += alignup((size_t)NB * 8);
    int*   wgctr  = (int*)p;    p += 256;
    // ---- everything above is zeroed by ONE memset ----
    size_t zlen = (size_t)(p - (char*)d_ws);
    int*   fcur   = (int*)p;    p += alignup((size_t)L * 4);
    int*   ent    = (int*)p;    p += alignup((size_t)KN * 4);
    int*   prim   = (int*)p;    p += alignup((size_t)KN * 4);
    int*   mlist  = (int*)p;    p += alignup((size_t)CAPM * 4);
    int*   nmulti = (int*)p;    p += 256;
    short* W1t    = (short*)p;  p += alignup((size_t)KOFF * CDIM * CDIM * 2);
    short* W2t    = (short*)p;  p += alignup((size_t)KOFF * CDIM * CDIM * 2);
    int*   zpage  = (int*)p;    p += 256;     // zeroed by prep
    short* sumbuf = (short*)p;  p += alignup((size_t)CAPM * CDIM * 2);  // 64 MB
    short* h1b    = (short*)p;                 // n*128 bf16 = 128 MB
    short* fb     = (short*)d_out;             // bf16 feat parks in d_out

    // rulebook + conversions
    hipMemsetAsync(cnt, 0, zlen, stream);      // cnt + agg + wgctr
    dim3 pg((n + 255) / 256, KOFF + 2);
    prep_kernel<<<pg, 256, 0, stream>>>(out_idx, mask, cnt, feat, fb,
                                        W1, W2, W1t, W2t, zpage, n, nelem / 8);
    scan_lb_kernel<<<NB, 256, 0, stream>>>(cnt, fcur, prim, mlist, nmulti,
                                           agg, wgctr, L, KN);
    dim3 fg((n + 255) / 256, KOFF);
    fill_kernel<<<fg, 256, 0, stream>>>(out_idx, in_idx, mask, cnt, fcur, ent, prim, n);

    const int ntile = n / ROWS;                        // 31250 exact
    const int tpb   = (ntile + NBLK - 1) / NBLK;       // 62

    // conv1
    merge_kernel<<<1024, 256, 0, stream>>>(fb, fcur, cnt, ent, mlist, nmulti, sumbuf);
    conv_kernel<0><<<NBLK, NTHR, 0, stream>>>(
        fb, sumbuf, W1t, prim, (const char*)zpage, gamma1, beta1, mean1, var1,
        nullptr, h1b, n, ntile, tpb);
    // conv2 (sumbuf recomputed from h1b)
    merge_kernel<<<1024, 256, 0, stream>>>(h1b, fcur, cnt, ent, mlist, nmulti, sumbuf);
    conv_kernel<1><<<NBLK, NTHR, 0, stream>>>(
        h1b, sumbuf, W2t, prim, (const char*)zpage, gamma2, beta2, mean2, var2,
        feat, d_out, n, ntile, tpb);
}

// Round 17
// 613.590 us; speedup vs baseline: 2.5694x; 1.0103x over previous
//
#include <hip/hip_runtime.h>

#define CDIM 128
#define KOFF 4
#define EPS 1e-4f
#define SCAN_CHUNK 2048   // 256 threads * 8 elems
#define ROWS 16           // output rows per tile (n % 16 == 0)
#define NBUF 4            // LDS ring buffers -> prefetch depth 3
#define NBLK 512          // persistent conv blocks (2 per CU)
#define NTHR 512          // 8 waves per block
#define CAPM (1 << 18)    // multi-bucket capacity (input has ~180k)

typedef __attribute__((ext_vector_type(8))) short bf16x8;
typedef __attribute__((ext_vector_type(4))) float f32x4;

__device__ __forceinline__ unsigned short f2bf(float f) {
    unsigned int u = __builtin_bit_cast(unsigned int, f);
    u += 0x7fffu + ((u >> 16) & 1u);          // round-to-nearest-even
    return (unsigned short)(u >> 16);
}
__device__ __forceinline__ float bf2f(unsigned short h) {
    unsigned int u = ((unsigned int)h) << 16;
    return __builtin_bit_cast(float, u);
}

// async global->LDS, 16B/lane; LDS dest = wave-uniform base + lane*16
__device__ __forceinline__ void gload_lds16(const void* g, void* l) {
    __builtin_amdgcn_global_load_lds(
        (const __attribute__((address_space(1))) void*)g,
        (__attribute__((address_space(3))) void*)l, 16, 0, 0);
}

// ---------------------------------------------------------------------------
// prep: fused {count (y<4)} + {feat cvt (y==4)} + {W cvt + zpage zero (y==5)}
// ---------------------------------------------------------------------------
__global__ __launch_bounds__(256) void prep_kernel(
    const int* __restrict__ out_idx, const int* __restrict__ mask,
    int* __restrict__ cnt, const float* __restrict__ feat,
    short* __restrict__ fb,
    const float* __restrict__ W1, const float* __restrict__ W2,
    short* __restrict__ W1t, short* __restrict__ W2t, int* __restrict__ zpage,
    int n, size_t total8)
{
    if (blockIdx.y == KOFF) {                      // cvt slice, grid-stride
        size_t stride = (size_t)gridDim.x * 256;
        for (size_t i = (size_t)blockIdx.x * 256 + threadIdx.x; i < total8; i += stride) {
            float4 a = ((const float4*)feat)[i * 2];
            float4 b = ((const float4*)feat)[i * 2 + 1];
            bf16x8 v;
            v[0] = (short)f2bf(a.x); v[1] = (short)f2bf(a.y);
            v[2] = (short)f2bf(a.z); v[3] = (short)f2bf(a.w);
            v[4] = (short)f2bf(b.x); v[5] = (short)f2bf(b.y);
            v[6] = (short)f2bf(b.z); v[7] = (short)f2bf(b.w);
            ((bf16x8*)fb)[i] = v;
        }
    } else if (blockIdx.y == KOFF + 1) {           // W convert + zpage zero
        if (blockIdx.x == 0 && threadIdx.x < 64) zpage[threadIdx.x] = 0;
        int idx = blockIdx.x * 256 + threadIdx.x;  // [k][co][ci]
        if (idx >= KOFF * CDIM * CDIM) return;
        int ci = idx & (CDIM - 1);
        int co = (idx >> 7) & (CDIM - 1);
        int k  = idx >> 14;
        size_t src = (size_t)k * CDIM * CDIM + (size_t)ci * CDIM + co;
        W1t[idx] = (short)f2bf(W1[src]);
        W2t[idx] = (short)f2bf(W2[src]);
    } else {
        int i = blockIdx.x * 256 + threadIdx.x;
        if (i >= n) return;
        int k = blockIdx.y;
        size_t s = (size_t)k * n + i;
        if (mask[s]) atomicAdd(&cnt[(size_t)out_idx[s] * KOFF + k], 1);
    }
}

// ---------------------------------------------------------------------------
// Single-kernel decoupled-lookback dual scan, WAVE-PARALLEL lookback window.
//   agg[bid] u64: state[63:62] (0 invalid, 1 aggregate, 2 inclusive),
//                 sum[55:24], multi[23:0].  Device-scope atomics only.
//   Wave 0 reads 64 predecessors at once; ballot finds nearest inclusive;
//   wave-reduce sums the window  ->  <=16 hops for 977 blocks (R16 bug:
//   single-thread walk = up to 976 serial cross-XCD atomic reads).
// ---------------------------------------------------------------------------
__device__ __forceinline__ unsigned long long lb_pack(int st, int s, int m) {
    return ((unsigned long long)st << 62) |
           ((unsigned long long)(unsigned)s << 24) |
           (unsigned long long)(unsigned)m;
}

__global__ __launch_bounds__(256) void scan_lb_kernel(
    const int* __restrict__ cnt, int* __restrict__ fcur, int* __restrict__ prim,
    int* __restrict__ mlist, int* __restrict__ nmulti,
    unsigned long long* __restrict__ agg, int* __restrict__ wgctr, int L, int KN)
{
    __shared__ int ts[256], ms[256];
    __shared__ int s_bid, s_ps, s_pm;
    int t = threadIdx.x;
    if (t == 0) s_bid = atomicAdd(wgctr, 1);      // dynamic order = schedule order
    __syncthreads();
    const int bid = s_bid;
    int base = bid * SCAN_CHUNK + t * 8;

    int v[8]; int s = 0, m = 0;
    #pragma unroll
    for (int u = 0; u < 8; ++u) {
        int i = base + u;
        v[u] = (i < L) ? cnt[i] : 0;
        s += v[u]; m += (v[u] >= 2);
    }
    ts[t] = s; ms[t] = m;
    __syncthreads();
    for (int d = 1; d < 256; d <<= 1) {
        int x = ts[t], y = ms[t];
        if (t >= d) { x += ts[t - d]; y += ms[t - d]; }
        __syncthreads();
        ts[t] = x; ms[t] = y;
        __syncthreads();
    }
    const int bs = ts[255], bm = ms[255];

    if (bid == 0) {
        if (t == 0) {
            s_ps = 0; s_pm = 0;
            atomicExch(&agg[0], lb_pack(2, bs, bm));
        }
    } else {
        // post aggregate immediately to unblock successors
        if (t == 0) atomicExch(&agg[bid], lb_pack(1, bs, bm));
        if (t < 64) {
            const int lane = t;
            int exs = 0, exm = 0;
            int pred = bid - 1;
            for (;;) {
                int idx = pred - lane;
                unsigned long long x;
                if (idx >= 0) {
                    do { x = atomicAdd(&agg[idx], 0ULL); } while ((x >> 62) == 0ULL);
                } else {
                    x = lb_pack(1, 0, 0);       // identity aggregate
                }
                unsigned long long incm = __ballot(((x >> 62) == 2ULL) && (idx >= 0));
                int firstinc = incm ? (__ffsll(incm) - 1) : 64;
                int cs = (lane <= firstinc) ? (int)((x >> 24) & 0xFFFFFFFFULL) : 0;
                int cm = (lane <= firstinc) ? (int)(x & 0xFFFFFFULL) : 0;
                #pragma unroll
                for (int d = 32; d > 0; d >>= 1) {
                    cs += __shfl_down(cs, d);
                    cm += __shfl_down(cm, d);
                }
                cs = __shfl(cs, 0); cm = __shfl(cm, 0);
                exs += cs; exm += cm;
                if (firstinc < 64) break;       // hit an inclusive predecessor
                pred -= 64;                     // block 0 is always inclusive
            }
            if (lane == 0) {
                s_ps = exs; s_pm = exm;
                atomicExch(&agg[bid], lb_pack(2, exs + bs, exm + bm));
            }
        }
    }
    __syncthreads();

    int pre  = s_ps + ((t == 0) ? 0 : ts[t - 1]);
    int mpre = s_pm + ((t == 0) ? 0 : ms[t - 1]);
    #pragma unroll
    for (int u = 0; u < 8; ++u) {
        int i = base + u;
        if (i < L) {
            fcur[i] = pre;
            if (i < KN) {
                int c = v[u];
                if (c == 0) prim[i] = -1;
                else if (c >= 2) {
                    if (mpre < CAPM) { prim[i] = 0x40000000 | mpre; mlist[mpre] = i; }
                    else prim[i] = -1;
                }
            } else {
                nmulti[0] = mpre;
            }
            pre += v[u]; mpre += (v[u] >= 2);
        }
    }
}

__global__ __launch_bounds__(256) void fill_kernel(
    const int* __restrict__ out_idx, const int* __restrict__ in_idx,
    const int* __restrict__ mask, const int* __restrict__ cnt,
    int* __restrict__ fcur, int* __restrict__ ent, int* __restrict__ prim, int n)
{
    int i = blockIdx.x * 256 + threadIdx.x;
    if (i >= n) return;
    int k = blockIdx.y;
    size_t s = (size_t)k * n + i;
    if (mask[s]) {
        int j = out_idx[s];
        size_t b = (size_t)j * KOFF + k;
        int src = in_idx[s];
        if (cnt[b] == 1) prim[b] = src;                 // single: direct, no atomic
        else { int pos = atomicAdd(&fcur[b], 1); ent[pos] = src; }
    }
}
// post-fill: for multi buckets fcur[b] = END; start = fcur[b] - cnt[b]

// ---------------------------------------------------------------------------
// merge: sumbuf[i] = bf16( sum of X rows of multi-bucket mlist[i] )
// ---------------------------------------------------------------------------
__global__ __launch_bounds__(256) void merge_kernel(
    const short* __restrict__ Xb, const int* __restrict__ fcur,
    const int* __restrict__ cnt, const int* __restrict__ ent,
    const int* __restrict__ mlist, const int* __restrict__ nmulti,
    short* __restrict__ sumbuf)
{
    int nm = *nmulti; if (nm > CAPM) nm = CAPM;
    int grp  = (blockIdx.x * 256 + threadIdx.x) >> 5;
    int gl   = threadIdx.x & 31;
    int ngrp = (gridDim.x * 256) >> 5;
    for (int i = grp; i < nm; i += ngrp) {
        int b  = mlist[i];
        int e1 = fcur[b];
        int e0 = e1 - cnt[b];
        float a0 = 0.f, a1 = 0.f, a2 = 0.f, a3 = 0.f;
        for (int e = e0; e < e1; ++e) {
            int src = ent[e];
            ushort4 v = *((const ushort4*)(Xb + (size_t)src * CDIM) + gl);
            a0 += bf2f(v.x); a1 += bf2f(v.y); a2 += bf2f(v.z); a3 += bf2f(v.w);
        }
        ushort4 o;
        o.x = f2bf(a0); o.y = f2bf(a1); o.z = f2bf(a2); o.w = f2bf(a3);
        *((ushort4*)(sumbuf + (size_t)i * CDIM) + gl) = o;
    }
}

// ---------------------------------------------------------------------------
// Persistent weight-stationary conv, depth-3 DMA pipeline, 2 barriers/tile.
// (unchanged from R16: 159 us/conv measured)
// ---------------------------------------------------------------------------
template <int EPI>
__global__ __launch_bounds__(NTHR, 4) void conv_kernel(
    const short* __restrict__ Xb, const short* __restrict__ sumbuf,
    const short* __restrict__ Wt, const int* __restrict__ prim,
    const char* __restrict__ zpage,
    const float* __restrict__ gamma, const float* __restrict__ beta,
    const float* __restrict__ mean, const float* __restrict__ var,
    const float* __restrict__ feat, void* __restrict__ Yv,
    int n, int ntile, int tpb)
{
    const int t    = threadIdx.x;
    const int w    = t >> 6;                   // wave 0..7
    const int lane = t & 63;

    __shared__ alignas(16) short As[NBUF][ROWS * 512];   // 4 x 16 KB ring
    __shared__ alignas(16) float s_scale[CDIM], s_shift[CDIM];

    if (t < CDIM) {
        float sc = gamma[t] * rsqrtf(var[t] + EPS);
        s_scale[t] = sc;
        s_shift[t] = beta[t] - mean[t] * sc;
    }
    __syncthreads();

    int t0 = blockIdx.x * tpb;
    int t1 = min(t0 + tpb, ntile);
    if (t0 >= t1) return;

    const int q    = lane >> 4;                // k segment (staging)
    const int p    = lane & 15;                // 16B chunk in segment
    const int lrow = lane & 15;
    const int g2   = lane >> 4;
    const int col  = w * 16 + lrow;            // this thread's cout column

    const float csc = s_scale[col];
    const float csh = s_shift[col];

    // ---- W cout-16 slice -> VGPRs, once per block (16 frags = 64 VGPR) ----
    bf16x8 wfr[16];
    #pragma unroll
    for (int ks = 0; ks < 16; ++ks) {
        int k  = ks >> 2;
        int kk = ks & 3;
        wfr[ks] = *(const bf16x8*)(Wt + (size_t)k * CDIM * CDIM
                                   + (w * 16 + lrow) * CDIM + kk * 32 + g2 * 8);
    }

    auto LOADP = [&](int ti, int* pr) {
        int tc = (ti < t1) ? ti : (t1 - 1);    // clamp: tail loads stay issued
        int j0 = tc * ROWS;
        #pragma unroll
        for (int i = 0; i < 2; ++i)
            pr[i] = prim[(size_t)(j0 + w * 2 + i) * KOFF + q];
    };
    auto STAGE = [&](const int* pr, int buf) {
        #pragma unroll
        for (int i = 0; i < 2; ++i) {
            int jl = w * 2 + i;
            int boff = ((p ^ (jl & 7)) << 4);
            int pv = pr[i];
            const char* g;
            if (pv < 0)               g = zpage + boff;
            else if (pv & 0x40000000) g = (const char*)sumbuf + ((size_t)(pv & 0x3FFFFFFF) << 8) + boff;
            else                      g = (const char*)Xb + ((size_t)pv << 8) + boff;
            gload_lds16(g, (char*)As[buf] + jl * 1024);
        }
    };

    // one pipeline iteration; VMW = exact counted vmcnt for this position
    auto ITER = [&](int ti, int rb, int sb, const int* prS, int* prL, auto&& VMW) {
        // residual preloads (EPI1) in C-fragment layout, issued first
        float fres[4];
        if (EPI == 1) {
            #pragma unroll
            for (int jj = 0; jj < 4; ++jj)
                fres[jj] = feat[(size_t)(ti * ROWS + g2 * 4 + jj) * CDIM + col];
        }
        STAGE(prS, sb);                        // tile ti+3 -> buffer sb
        LOADP(ti + 4, prL);                    // prim for tile ti+4
        __builtin_amdgcn_sched_barrier(0);     // pin window before the wait
        VMW();                                 // tile ti's DMAs provably done
        __builtin_amdgcn_s_barrier();          // B1: As[rb] ready
        __builtin_amdgcn_sched_barrier(0);

        f32x4 acc = (f32x4){0.f, 0.f, 0.f, 0.f};
        __builtin_amdgcn_s_setprio(1);
        #pragma unroll
        for (int ks = 0; ks < 16; ++ks) {
            int cb = ks * 4 + g2;
            bf16x8 a = *(const bf16x8*)(&As[rb][lrow * 512 + ((cb ^ (lrow & 7)) << 3)]);
            acc = __builtin_amdgcn_mfma_f32_16x16x32_bf16(a, wfr[ks], acc, 0, 0, 0);
        }
        __builtin_amdgcn_s_setprio(0);
        asm volatile("s_waitcnt lgkmcnt(0)" ::: "memory");
        __builtin_amdgcn_s_barrier();          // B2: As[rb] reads done -> reusable

        // direct epilogue: BN in regs, per-16-lane-group contiguous row chunks
        if (EPI == 0) {
            unsigned short* out = (unsigned short*)Yv;
            #pragma unroll
            for (int jj = 0; jj < 4; ++jj) {
                int row = ti * ROWS + g2 * 4 + jj;
                out[(size_t)row * CDIM + col] = f2bf(fmaxf(acc[jj] * csc + csh, 0.f));
            }
        } else {
            float* out = (float*)Yv;
            #pragma unroll
            for (int jj = 0; jj < 4; ++jj) {
                int row = ti * ROWS + g2 * 4 + jj;
                out[(size_t)row * CDIM + col] = acc[jj] * csc + csh + fres[jj];
            }
        }
        __builtin_amdgcn_sched_barrier(0);     // pin stores inside this window
    };

    #define VMW_LIT(N0, N1)                                                     \
        [] {                                                                    \
            if (EPI == 0) asm volatile("s_waitcnt vmcnt(" #N0 ")" ::: "memory");\
            else          asm volatile("s_waitcnt vmcnt(" #N1 ")" ::: "memory");\
        }

    int p0[2], p1[2], p2[2], p3[2];
    LOADP(t0,     p0);
    LOADP(t0 + 1, p1);
    LOADP(t0 + 2, p2);
    STAGE(p0, 0);
    STAGE(p1, 1);
    STAGE(p2, 2);
    LOADP(t0 + 3, p3);

    // ramp (exact counts; block-uniform guards keep barriers safe)
    ITER(t0 + 0, 0, 3, p3, p0, VMW_LIT(10, 14));
    if (t0 + 1 < t1) {
        ITER(t0 + 1, 1, 0, p0, p1, VMW_LIT(16, 24));
        if (t0 + 2 < t1) {
            ITER(t0 + 2, 2, 1, p1, p2, VMW_LIT(22, 34));
            if (t0 + 3 < t1) {
                ITER(t0 + 3, 3, 2, p2, p3, VMW_LIT(26, 38));
                for (int ti = t0 + 4; ti < t1; ti += 4) {
                    ITER(ti, 0, 3, p3, p0, VMW_LIT(26, 38));
                    if (ti + 1 >= t1) break;
                    ITER(ti + 1, 1, 0, p0, p1, VMW_LIT(26, 38));
                    if (ti + 2 >= t1) break;
                    ITER(ti + 2, 2, 1, p1, p2, VMW_LIT(26, 38));
                    if (ti + 3 >= t1) break;
                    ITER(ti + 3, 3, 2, p2, p3, VMW_LIT(26, 38));
                }
            }
        }
    }
    #undef VMW_LIT
}

extern "C" void kernel_launch(void* const* d_in, const int* in_sizes, int n_in,
                              void* d_out, int out_size, void* d_ws, size_t ws_size,
                              hipStream_t stream)
{
    const float* feat   = (const float*)d_in[0];
    const float* W1     = (const float*)d_in[1];
    const float* W2     = (const float*)d_in[2];
    const float* gamma1 = (const float*)d_in[3];
    const float* beta1  = (const float*)d_in[4];
    const float* mean1  = (const float*)d_in[5];
    const float* var1   = (const float*)d_in[6];
    const float* gamma2 = (const float*)d_in[7];
    const float* beta2  = (const float*)d_in[8];
    const float* mean2  = (const float*)d_in[9];
    const float* var2   = (const float*)d_in[10];
    const int* in_idx   = (const int*)d_in[11];
    const int* out_idx  = (const int*)d_in[12];
    const int* mask     = (const int*)d_in[13];

    const int n  = in_sizes[0] / CDIM;     // 500000 (src < 2^19, n % 16 == 0)
    const int KN = KOFF * n;
    const int L  = KN + 1;
    const int NB = (L + SCAN_CHUNK - 1) / SCAN_CHUNK;   // 977
    const size_t nelem = (size_t)n * CDIM;

    auto alignup = [](size_t x) { return (x + 255) & ~(size_t)255; };
    char* p = (char*)d_ws;
    int*   cnt    = (int*)p;    p += alignup((size_t)L * 4);
    unsigned long long* agg = (unsigned long long*)p; p += alignup((size_t)NB * 8);
    int*   wgctr  = (int*)p;    p += 256;
    // ---- everything above is zeroed by ONE memset ----
    size_t zlen = (size_t)(p - (char*)d_ws);
    int*   fcur   = (int*)p;    p += alignup((size_t)L * 4);
    int*   ent    = (int*)p;    p += alignup((size_t)KN * 4);
    int*   prim   = (int*)p;    p += alignup((size_t)KN * 4);
    int*   mlist  = (int*)p;    p += alignup((size_t)CAPM * 4);
    int*   nmulti = (int*)p;    p += 256;
    short* W1t    = (short*)p;  p += alignup((size_t)KOFF * CDIM * CDIM * 2);
    short* W2t    = (short*)p;  p += alignup((size_t)KOFF * CDIM * CDIM * 2);
    int*   zpage  = (int*)p;    p += 256;     // zeroed by prep
    short* sumbuf = (short*)p;  p += alignup((size_t)CAPM * CDIM * 2);  // 64 MB
    short* h1b    = (short*)p;                 // n*128 bf16 = 128 MB
    short* fb     = (short*)d_out;             // bf16 feat parks in d_out

    // rulebook + conversions
    hipMemsetAsync(cnt, 0, zlen, stream);      // cnt + agg + wgctr
    dim3 pg((n + 255) / 256, KOFF + 2);
    prep_kernel<<<pg, 256, 0, stream>>>(out_idx, mask, cnt, feat, fb,
                                        W1, W2, W1t, W2t, zpage, n, nelem / 8);
    scan_lb_kernel<<<NB, 256, 0, stream>>>(cnt, fcur, prim, mlist, nmulti,
                                           agg, wgctr, L, KN);
    dim3 fg((n + 255) / 256, KOFF);
    fill_kernel<<<fg, 256, 0, stream>>>(out_idx, in_idx, mask, cnt, fcur, ent, prim, n);

    const int ntile = n / ROWS;                        // 31250 exact
    const int tpb   = (ntile + NBLK - 1) / NBLK;       // 62

    // conv1
    merge_kernel<<<1024, 256, 0, stream>>>(fb, fcur, cnt, ent, mlist, nmulti, sumbuf);
    conv_kernel<0><<<NBLK, NTHR, 0, stream>>>(
        fb, sumbuf, W1t, prim, (const char*)zpage, gamma1, beta1, mean1, var1,
        nullptr, h1b, n, ntile, tpb);
    // conv2 (sumbuf recomputed from h1b)
    merge_kernel<<<1024, 256, 0, stream>>>(h1b, fcur, cnt, ent, mlist, nmulti, sumbuf);
    conv_kernel<1><<<NBLK, NTHR, 0, stream>>>(
        h1b, sumbuf, W2t, prim, (const char*)zpage, gamma2, beta2, mean2, var2,
        feat, d_out, n, ntile, tpb);
}